// Round 3
// baseline (60.588 us; speedup 1.0000x reference)
//
#include <hip/hip_runtime.h>
#include <hip/hip_bf16.h>

// Fused causal self-attention: B=4096 independent (T=64, C=64) problems.
// ONE WAVE per batch, 2 waves (2 batches) per 128-thread block, 2048 blocks.
// All matmuls are v_mfma_f32_16x16x32_bf16. K=16 sub-results are PAIRED into
// K=32 operands (valid: MFMA contracts over hw k-positions; permuting the
// k-axis identically on A and B preserves the sum).
// Register budget ~120 (forced <=128 by __launch_bounds__(128,4)):
//   - qT frags live in LDS (8KB/wave), read back 2 frags per column tile
//   - score/softmax/PV/projection processed one 16-col tile at a time
// Zero barriers (all LDS traffic is wave-private).

typedef __attribute__((ext_vector_type(8))) short bf16x8;
typedef __attribute__((ext_vector_type(4))) short bf16x4;
typedef __attribute__((ext_vector_type(4))) float f32x4;

#define MFMA32(a, b, c) __builtin_amdgcn_mfma_f32_16x16x32_bf16(a, b, c, 0, 0, 0)
#define LOG2E 1.44269504088896f

__device__ __forceinline__ unsigned short f2b(float f) {
    return __builtin_bit_cast(unsigned short, __float2bfloat16(f));   // RNE
}

__device__ __forceinline__ bf16x4 pack4(f32x4 a, float s) {
    bf16x4 r;
    r[0] = (short)f2b(a[0] * s); r[1] = (short)f2b(a[1] * s);
    r[2] = (short)f2b(a[2] * s); r[3] = (short)f2b(a[3] * s);
    return r;
}

__device__ __forceinline__ bf16x4 zero4() {
    bf16x4 r; r[0] = 0; r[1] = 0; r[2] = 0; r[3] = 0; return r;
}

__device__ __forceinline__ bf16x8 cat(bf16x4 lo, bf16x4 hi) {
    bf16x8 r;
    r[0] = lo[0]; r[1] = lo[1]; r[2] = lo[2]; r[3] = lo[3];
    r[4] = hi[0]; r[5] = hi[1]; r[6] = hi[2]; r[7] = hi[3];
    return r;
}

// load 8 consecutive f32 from global, convert to a bf16x8 fragment
__device__ __forceinline__ bf16x8 xfrag(const float* p) {
    const float4 a = *(const float4*)p;
    const float4 b = *(const float4*)(p + 4);
    bf16x8 r;
    r[0] = (short)f2b(a.x); r[1] = (short)f2b(a.y);
    r[2] = (short)f2b(a.z); r[3] = (short)f2b(a.w);
    r[4] = (short)f2b(b.x); r[5] = (short)f2b(b.y);
    r[6] = (short)f2b(b.z); r[7] = (short)f2b(b.w);
    return r;
}

// ---- pre-kernel: convert the 4 weight matrices fp32 -> bf16 into d_ws ----
__global__ void cvt_w_kernel(const float* __restrict__ wk, const float* __restrict__ wq,
                             const float* __restrict__ wv, const float* __restrict__ wp,
                             unsigned short* __restrict__ dst) {
    int e = blockIdx.x * 256 + threadIdx.x;   // 0..16383
    int m = e >> 12;
    int off = e & 4095;
    const float* src = (m == 0) ? wk : (m == 1) ? wq : (m == 2) ? wv : wp;
    dst[e] = f2b(src[off]);
}

__global__ __launch_bounds__(128, 4) void attn_fused_kernel(
    const float* __restrict__ x,              // [4096,64,64] fp32
    const unsigned short* __restrict__ wbf,   // bf16: Wk,Wq,Wv,Wp each [64][64] row-major
    const float* __restrict__ bp,             // [64] fp32
    float* __restrict__ out)                  // [4096,64,64] fp32
{
    __shared__ short qlds[2 * 8 * 64 * 8];    // 2 waves x 8 frags x 64 lanes x 16B = 16KB

    const int tid  = threadIdx.x;
    const int wv_  = tid >> 6;
    const int lane = tid & 63;
    const int r = lane & 15;      // frag col / A-row index
    const int g = lane >> 4;      // lane group: D rows g*4+j; K32 k = g*8+e
    short* qbase = qlds + wv_ * (8 * 64 * 8);

    const long b = (long)blockIdx.x * 2 + wv_;
    const float* xb = x + b * 4096;
    const unsigned short* Wk = wbf;
    const unsigned short* Wq = wbf + 4096;
    const unsigned short* Wv = wbf + 8192;
    const unsigned short* Wp = wbf + 12288;

    // ---- x fragments (K=32): lane holds x[t][c], t = tt*16+r, c = ch*32+g*8+e.
    // Dual use: B-frag of (W @ xT) and A-frag of (x @ WvT).
    bf16x8 xf[4][2];
    #pragma unroll
    for (int tt = 0; tt < 4; ++tt)
        #pragma unroll
        for (int ch = 0; ch < 2; ++ch)
            xf[tt][ch] = xfrag(xb + (tt * 16 + r) * 64 + ch * 32 + g * 8);

    // ---- qT = Wq @ xT (scaled 1/8): paired cm-tiles -> LDS (frag id = cm2*4 + tt) ----
    #pragma unroll
    for (int cm2 = 0; cm2 < 2; ++cm2) {
        bf16x4 qlo[4];
        #pragma unroll
        for (int h = 0; h < 2; ++h) {
            const int cm = cm2 * 2 + h;
            bf16x8 a0 = *(const bf16x8*)(Wq + (cm * 16 + r) * 64 + g * 8);
            bf16x8 a1 = *(const bf16x8*)(Wq + (cm * 16 + r) * 64 + 32 + g * 8);
            #pragma unroll
            for (int tt = 0; tt < 4; ++tt) {
                f32x4 acc = {0.f, 0.f, 0.f, 0.f};
                acc = MFMA32(a0, xf[tt][0], acc);
                acc = MFMA32(a1, xf[tt][1], acc);
                if (h == 0) qlo[tt] = pack4(acc, 0.125f);
                else *(bf16x8*)(qbase + ((cm2 * 4 + tt) * 64 + lane) * 8)
                         = cat(qlo[tt], pack4(acc, 0.125f));
            }
        }
    }

    // ---- kT = Wk @ xT: paired cm-tiles kept in regs: kT8[cm2][sm] ----
    bf16x8 kT8[2][4];
    #pragma unroll
    for (int cm2 = 0; cm2 < 2; ++cm2) {
        bf16x4 klo[4];
        #pragma unroll
        for (int h = 0; h < 2; ++h) {
            const int cm = cm2 * 2 + h;
            bf16x8 a0 = *(const bf16x8*)(Wk + (cm * 16 + r) * 64 + g * 8);
            bf16x8 a1 = *(const bf16x8*)(Wk + (cm * 16 + r) * 64 + 32 + g * 8);
            #pragma unroll
            for (int sm = 0; sm < 4; ++sm) {
                f32x4 acc = {0.f, 0.f, 0.f, 0.f};
                acc = MFMA32(a0, xf[sm][0], acc);
                acc = MFMA32(a1, xf[sm][1], acc);
                if (h == 0) klo[sm] = pack4(acc, 1.0f);
                else kT8[cm2][sm] = cat(klo[sm], pack4(acc, 1.0f));
            }
        }
    }

    // ---- v = x @ WvT: paired s-tiles: v8[cm][sm2] (A-operand of PV) ----
    bf16x8 v8[4][2];
    #pragma unroll
    for (int cm = 0; cm < 4; ++cm) {
        bf16x8 b0 = *(const bf16x8*)(Wv + (cm * 16 + r) * 64 + g * 8);
        bf16x8 b1 = *(const bf16x8*)(Wv + (cm * 16 + r) * 64 + 32 + g * 8);
        bf16x4 tmp[4];
        #pragma unroll
        for (int tv = 0; tv < 4; ++tv) {
            f32x4 acc = {0.f, 0.f, 0.f, 0.f};
            acc = MFMA32(xf[tv][0], b0, acc);
            acc = MFMA32(xf[tv][1], b1, acc);
            tmp[tv] = pack4(acc, 1.0f);
        }
        v8[cm][0] = cat(tmp[0], tmp[1]);
        v8[cm][1] = cat(tmp[2], tmp[3]);
    }
    // xf dead from here.

    float* ob = out + b * 4096;

    // ---- per 16-column tile: scores -> softmax -> PV -> projection -> store ----
    #pragma unroll
    for (int tn = 0; tn < 4; ++tn) {
        bf16x8 q0 = *(const bf16x8*)(qbase + ((0 * 4 + tn) * 64 + lane) * 8);
        bf16x8 q1 = *(const bf16x8*)(qbase + ((1 * 4 + tn) * 64 + lane) * 8);

        // ST[s][t] column: per lane t = tn*16+r, s = sm*16 + g*4 + j
        f32x4 st[4];
        #pragma unroll
        for (int sm = 0; sm < 4; ++sm) {
            if (sm > tn) continue;
            f32x4 acc = {0.f, 0.f, 0.f, 0.f};
            acc = MFMA32(kT8[0][sm], q0, acc);
            acc = MFMA32(kT8[1][sm], q1, acc);
            st[sm] = acc;
        }

        // column softmax (reduce over sm-tiles in-reg + lane bits 4,5)
        float mx = -1e30f;
        #pragma unroll
        for (int sm = 0; sm < 4; ++sm) {
            if (sm > tn) continue;
            #pragma unroll
            for (int j = 0; j < 4; ++j) {
                float v = st[sm][j];
                if (sm == tn) v = ((g * 4 + j) <= r) ? v : -1e30f;  // causal
                st[sm][j] = v;
                mx = fmaxf(mx, v);
            }
        }
        mx = fmaxf(mx, __shfl_xor(mx, 16));
        mx = fmaxf(mx, __shfl_xor(mx, 32));
        float sum = 0.f;
        #pragma unroll
        for (int sm = 0; sm < 4; ++sm) {
            if (sm > tn) continue;
            #pragma unroll
            for (int j = 0; j < 4; ++j) {
                float e = exp2f((st[sm][j] - mx) * LOG2E);
                st[sm][j] = e;
                sum += e;
            }
        }
        sum += __shfl_xor(sum, 16);
        sum += __shfl_xor(sum, 32);
        float inv = __builtin_amdgcn_rcpf(sum);   // sum >= 1 (diagonal present)

        bf16x4 ph[4];
        #pragma unroll
        for (int sm = 0; sm < 4; ++sm)
            ph[sm] = (sm <= tn) ? pack4(st[sm], inv) : zero4();
        bf16x8 pt80 = cat(ph[0], ph[1]);
        bf16x8 pt81 = cat(ph[2], ph[3]);

        // out2T column: o2[c][t-col] = sum_s v[s][c] P[t][s]
        bf16x4 o2c[4];
        #pragma unroll
        for (int cm = 0; cm < 4; ++cm) {
            f32x4 acc = {0.f, 0.f, 0.f, 0.f};
            acc = MFMA32(v8[cm][0], pt80, acc);
            if (tn >= 2) acc = MFMA32(v8[cm][1], pt81, acc);
            o2c[cm] = pack4(acc, 1.0f);
        }
        bf16x8 o280 = cat(o2c[0], o2c[1]);
        bf16x8 o281 = cat(o2c[2], o2c[3]);

        // resT column: res[t][o] = sum_c Wp[o][c] o2[c][t] + bp[o]
        #pragma unroll
        for (int om = 0; om < 4; ++om) {
            const unsigned short* wrow = Wp + (om * 16 + r) * 64 + g * 4;
            bf16x8 w0 = cat(*(const bf16x4*)(wrow),      *(const bf16x4*)(wrow + 16));
            bf16x8 w1 = cat(*(const bf16x4*)(wrow + 32), *(const bf16x4*)(wrow + 48));
            f32x4 acc = {0.f, 0.f, 0.f, 0.f};
            acc = MFMA32(w0, o280, acc);
            acc = MFMA32(w1, o281, acc);
            const float4 bias = *(const float4*)(bp + om * 16 + g * 4);
            float4 o;
            o.x = acc[0] + bias.x; o.y = acc[1] + bias.y;
            o.z = acc[2] + bias.z; o.w = acc[3] + bias.w;
            *(float4*)(ob + (tn * 16 + r) * 64 + om * 16 + g * 4) = o;
        }
    }
}

extern "C" void kernel_launch(void* const* d_in, const int* in_sizes, int n_in,
                              void* d_out, int out_size, void* d_ws, size_t ws_size,
                              hipStream_t stream) {
    const float* x  = (const float*)d_in[0];
    const float* wk = (const float*)d_in[1];
    const float* wq = (const float*)d_in[2];
    const float* wv = (const float*)d_in[3];
    const float* wp = (const float*)d_in[4];
    const float* bp = (const float*)d_in[5];
    unsigned short* wbf = (unsigned short*)d_ws;   // 16384 bf16 = 32 KB

    cvt_w_kernel<<<64, 256, 0, stream>>>(wk, wq, wv, wp, wbf);
    attn_fused_kernel<<<2048, 128, 0, stream>>>(x, wbf, bp, (float*)d_out);
}

// Round 4
// 58.288 us; speedup vs baseline: 1.0395x; 1.0395x over previous
//
#include <hip/hip_runtime.h>
#include <hip/hip_bf16.h>

// Fused causal self-attention: B=4096 independent (T=64, C=64) problems.
// ONE WAVE per batch, 4 waves per 256-thread block, 1024 blocks.
// All matmuls v_mfma_f32_16x16x32_bf16; K=16 D-frags paired into K=32 operands.
// Critical-path design: K,Q computed from x REGISTER frags; x and qT staged to
// wave-private LDS (16 writes + 16 reads per wave, zero barriers) for the V and
// score phases. Register peak ~110, forced <=128 by __launch_bounds__(256,4)
// -> 4 waves/SIMD, 16 waves/CU (2 blocks x 64KB LDS).

typedef __attribute__((ext_vector_type(8))) short bf16x8;
typedef __attribute__((ext_vector_type(4))) short bf16x4;
typedef __attribute__((ext_vector_type(4))) float f32x4;

#define MFMA32(a, b, c) __builtin_amdgcn_mfma_f32_16x16x32_bf16(a, b, c, 0, 0, 0)
#define LOG2E 1.44269504088896f

__device__ __forceinline__ unsigned short f2b(float f) {
    return __builtin_bit_cast(unsigned short, __float2bfloat16(f));   // RNE
}

__device__ __forceinline__ bf16x4 pack4(f32x4 a, float s) {
    bf16x4 r;
    r[0] = (short)f2b(a[0] * s); r[1] = (short)f2b(a[1] * s);
    r[2] = (short)f2b(a[2] * s); r[3] = (short)f2b(a[3] * s);
    return r;
}

__device__ __forceinline__ bf16x4 zero4() {
    bf16x4 r; r[0] = 0; r[1] = 0; r[2] = 0; r[3] = 0; return r;
}

__device__ __forceinline__ bf16x8 cat(bf16x4 lo, bf16x4 hi) {
    bf16x8 r;
    r[0] = lo[0]; r[1] = lo[1]; r[2] = lo[2]; r[3] = lo[3];
    r[4] = hi[0]; r[5] = hi[1]; r[6] = hi[2]; r[7] = hi[3];
    return r;
}

__device__ __forceinline__ bf16x8 cvt8(float4 a, float4 b) {
    bf16x8 r;
    r[0] = (short)f2b(a.x); r[1] = (short)f2b(a.y);
    r[2] = (short)f2b(a.z); r[3] = (short)f2b(a.w);
    r[4] = (short)f2b(b.x); r[5] = (short)f2b(b.y);
    r[6] = (short)f2b(b.z); r[7] = (short)f2b(b.w);
    return r;
}

// ---- pre-kernel: convert the 4 weight matrices fp32 -> bf16 into d_ws ----
__global__ void cvt_w_kernel(const float* __restrict__ wk, const float* __restrict__ wq,
                             const float* __restrict__ wv, const float* __restrict__ wp,
                             unsigned short* __restrict__ dst) {
    int e = blockIdx.x * 256 + threadIdx.x;   // 0..16383
    int m = e >> 12;
    int off = e & 4095;
    const float* src = (m == 0) ? wk : (m == 1) ? wq : (m == 2) ? wv : wp;
    dst[e] = f2b(src[off]);
}

__global__ __launch_bounds__(256, 4) void attn_fused_kernel(
    const float* __restrict__ x,              // [4096,64,64] fp32
    const unsigned short* __restrict__ wbf,   // bf16: Wk,Wq,Wv,Wp each [64][64] row-major
    const float* __restrict__ bp,             // [64] fp32
    float* __restrict__ out)                  // [4096,64,64] fp32
{
    __shared__ short lds[32768];              // 64 KB: 4 waves x (x:8KB + qT:8KB)

    const int tid  = threadIdx.x;
    const int wv_  = tid >> 6;
    const int lane = tid & 63;
    const int r = lane & 15;      // frag col / A-row index
    const int g = lane >> 4;      // lane group: D rows g*4+j; K32 k = g*8+e
    short* xls = lds + wv_ * 8192;            // x frags: id f = tt*2+ch
    short* qls = xls + 4096;                  // qT frags: id = cm2*4 + tt

    const long b = (long)blockIdx.x * 4 + wv_;
    const float* xb = x + b * 4096;
    const unsigned short* Wk = wbf;
    const unsigned short* Wq = wbf + 4096;
    const unsigned short* Wv = wbf + 8192;
    const unsigned short* Wp = wbf + 12288;

    // ---- phase 0: issue ALL x loads + Wk loads together (one HBM/L2 wait) ----
    float4 raw[8][2];
    #pragma unroll
    for (int f = 0; f < 8; ++f) {
        const float* p = xb + ((f >> 1) * 16 + r) * 64 + (f & 1) * 32 + g * 8;
        raw[f][0] = *(const float4*)p;
        raw[f][1] = *(const float4*)(p + 4);
    }
    bf16x8 wA0[4], wA1[4];
    #pragma unroll
    for (int cm = 0; cm < 4; ++cm) {
        wA0[cm] = *(const bf16x8*)(Wk + (cm * 16 + r) * 64 + g * 8);
        wA1[cm] = *(const bf16x8*)(Wk + (cm * 16 + r) * 64 + 32 + g * 8);
    }

    // ---- convert x to bf16 frags; stash to LDS (for V phase) while K uses regs ----
    bf16x8 xf[8];                             // frag f: t = (f>>1)*16+r, c = (f&1)*32+g*8..
    #pragma unroll
    for (int f = 0; f < 8; ++f) {
        xf[f] = cvt8(raw[f][0], raw[f][1]);
        *(bf16x8*)(xls + (f * 64 + lane) * 8) = xf[f];
    }

    // ---- K: kT = Wk @ xT, paired cm-tiles -> kT8[cm2][sm] (regs) ----
    bf16x8 kT8[2][4];
    #pragma unroll
    for (int sm = 0; sm < 4; ++sm) {
        bf16x4 h[4];
        #pragma unroll
        for (int cm = 0; cm < 4; ++cm) {
            f32x4 acc = {0.f, 0.f, 0.f, 0.f};
            acc = MFMA32(wA0[cm], xf[sm * 2], acc);
            acc = MFMA32(wA1[cm], xf[sm * 2 + 1], acc);
            h[cm] = pack4(acc, 1.0f);
        }
        kT8[0][sm] = cat(h[0], h[1]);
        kT8[1][sm] = cat(h[2], h[3]);
    }

    // ---- Q: qT = Wq @ xT (scaled 1/8) from x regs -> LDS ----
    #pragma unroll
    for (int cm = 0; cm < 4; ++cm) {
        wA0[cm] = *(const bf16x8*)(Wq + (cm * 16 + r) * 64 + g * 8);
        wA1[cm] = *(const bf16x8*)(Wq + (cm * 16 + r) * 64 + 32 + g * 8);
    }
    #pragma unroll
    for (int tt = 0; tt < 4; ++tt) {
        bf16x4 h[4];
        #pragma unroll
        for (int cm = 0; cm < 4; ++cm) {
            f32x4 acc = {0.f, 0.f, 0.f, 0.f};
            acc = MFMA32(wA0[cm], xf[tt * 2], acc);
            acc = MFMA32(wA1[cm], xf[tt * 2 + 1], acc);
            h[cm] = pack4(acc, 0.125f);
        }
        *(bf16x8*)(qls + ((0 * 4 + tt) * 64 + lane) * 8) = cat(h[0], h[1]);
        *(bf16x8*)(qls + ((1 * 4 + tt) * 64 + lane) * 8) = cat(h[2], h[3]);
    }
    // xf dead from here (x lives in LDS).

    // ---- V: v = x @ WvT, x frags re-read from LDS -> v8[cm][sm2] (regs) ----
    #pragma unroll
    for (int cm = 0; cm < 4; ++cm) {
        wA0[cm] = *(const bf16x8*)(Wv + (cm * 16 + r) * 64 + g * 8);
        wA1[cm] = *(const bf16x8*)(Wv + (cm * 16 + r) * 64 + 32 + g * 8);
    }
    bf16x8 v8[4][2];
    {
        bf16x4 tmp[4][4];
        #pragma unroll
        for (int tv = 0; tv < 4; ++tv) {
            bf16x8 x0 = *(const bf16x8*)(xls + ((tv * 2) * 64 + lane) * 8);
            bf16x8 x1 = *(const bf16x8*)(xls + ((tv * 2 + 1) * 64 + lane) * 8);
            #pragma unroll
            for (int cm = 0; cm < 4; ++cm) {
                f32x4 acc = {0.f, 0.f, 0.f, 0.f};
                acc = MFMA32(x0, wA0[cm], acc);
                acc = MFMA32(x1, wA1[cm], acc);
                tmp[tv][cm] = pack4(acc, 1.0f);
            }
        }
        #pragma unroll
        for (int cm = 0; cm < 4; ++cm) {
            v8[cm][0] = cat(tmp[0][cm], tmp[1][cm]);
            v8[cm][1] = cat(tmp[2][cm], tmp[3][cm]);
        }
    }

    float* ob = out + b * 4096;

    // ---- per 16-col tile: scores -> softmax -> PV -> projection -> store ----
    #pragma unroll
    for (int tn = 0; tn < 4; ++tn) {
        bf16x8 q0 = *(const bf16x8*)(qls + ((0 * 4 + tn) * 64 + lane) * 8);
        bf16x8 q1 = *(const bf16x8*)(qls + ((1 * 4 + tn) * 64 + lane) * 8);

        // ST column: per lane t = tn*16+r, s = sm*16 + g*4 + j
        f32x4 st[4];
        #pragma unroll
        for (int sm = 0; sm < 4; ++sm) {
            if (sm > tn) continue;
            f32x4 acc = {0.f, 0.f, 0.f, 0.f};
            acc = MFMA32(kT8[0][sm], q0, acc);
            acc = MFMA32(kT8[1][sm], q1, acc);
            st[sm] = acc;
        }

        // column softmax (reduce over sm-tiles in-reg + lane bits 4,5)
        float mx = -1e30f;
        #pragma unroll
        for (int sm = 0; sm < 4; ++sm) {
            if (sm > tn) continue;
            #pragma unroll
            for (int j = 0; j < 4; ++j) {
                float v = st[sm][j];
                if (sm == tn) v = ((g * 4 + j) <= r) ? v : -1e30f;  // causal
                st[sm][j] = v;
                mx = fmaxf(mx, v);
            }
        }
        mx = fmaxf(mx, __shfl_xor(mx, 16));
        mx = fmaxf(mx, __shfl_xor(mx, 32));
        float sum = 0.f;
        #pragma unroll
        for (int sm = 0; sm < 4; ++sm) {
            if (sm > tn) continue;
            #pragma unroll
            for (int j = 0; j < 4; ++j) {
                float e = exp2f((st[sm][j] - mx) * LOG2E);
                st[sm][j] = e;
                sum += e;
            }
        }
        sum += __shfl_xor(sum, 16);
        sum += __shfl_xor(sum, 32);
        float inv = __builtin_amdgcn_rcpf(sum);   // sum >= 1 (diagonal present)

        bf16x4 ph[4];
        #pragma unroll
        for (int sm = 0; sm < 4; ++sm)
            ph[sm] = (sm <= tn) ? pack4(st[sm], inv) : zero4();
        bf16x8 pt80 = cat(ph[0], ph[1]);
        bf16x8 pt81 = cat(ph[2], ph[3]);

        // out2T column: o2[c][t] = sum_s v[s][c] P[t][s]
        bf16x4 o2c[4];
        #pragma unroll
        for (int cm = 0; cm < 4; ++cm) {
            f32x4 acc = {0.f, 0.f, 0.f, 0.f};
            acc = MFMA32(v8[cm][0], pt80, acc);
            if (tn >= 2) acc = MFMA32(v8[cm][1], pt81, acc);
            o2c[cm] = pack4(acc, 1.0f);
        }
        bf16x8 o280 = cat(o2c[0], o2c[1]);
        bf16x8 o281 = cat(o2c[2], o2c[3]);

        // resT column: res[t][o] = sum_c Wp[o][c] o2[c][t] + bp[o]
        #pragma unroll
        for (int om = 0; om < 4; ++om) {
            const unsigned short* wrow = Wp + (om * 16 + r) * 64 + g * 4;
            bf16x8 w0 = cat(*(const bf16x4*)(wrow),      *(const bf16x4*)(wrow + 16));
            bf16x8 w1 = cat(*(const bf16x4*)(wrow + 32), *(const bf16x4*)(wrow + 48));
            f32x4 acc = {0.f, 0.f, 0.f, 0.f};
            acc = MFMA32(w0, o280, acc);
            acc = MFMA32(w1, o281, acc);
            const float4 bias = *(const float4*)(bp + om * 16 + g * 4);
            float4 o;
            o.x = acc[0] + bias.x; o.y = acc[1] + bias.y;
            o.z = acc[2] + bias.z; o.w = acc[3] + bias.w;
            *(float4*)(ob + (tn * 16 + r) * 64 + om * 16 + g * 4) = o;
        }
    }
}

extern "C" void kernel_launch(void* const* d_in, const int* in_sizes, int n_in,
                              void* d_out, int out_size, void* d_ws, size_t ws_size,
                              hipStream_t stream) {
    const float* x  = (const float*)d_in[0];
    const float* wk = (const float*)d_in[1];
    const float* wq = (const float*)d_in[2];
    const float* wv = (const float*)d_in[3];
    const float* wp = (const float*)d_in[4];
    const float* bp = (const float*)d_in[5];
    unsigned short* wbf = (unsigned short*)d_ws;   // 16384 bf16 = 32 KB

    cvt_w_kernel<<<64, 256, 0, stream>>>(wk, wq, wv, wp, wbf);
    attn_fused_kernel<<<1024, 256, 0, stream>>>(x, wbf, bp, (float*)d_out);
}

// Round 7
// 48.082 us; speedup vs baseline: 1.2601x; 1.2123x over previous
//
#include <hip/hip_runtime.h>
#include <hip/hip_bf16.h>

// Fused causal self-attention: B=4096 independent (T=64, C=64) problems.
// ONE WAVE per batch, 64-thread blocks, 4096 blocks -> with <=128 VGPR the
// whole grid is resident (4 waves/SIMD x 1024 SIMDs = 4096 waves).
// All matmuls v_mfma_f32_16x16x32_bf16; K=16 D-frags paired into K=32 operands.
// Softmax reductions: __shfl_xor over lane bits 4,5 (proven correct R2-R4;
// the R5/R6 permlane-swap experiments mis-reduced -- tied-operand hazard).
// 1/8 score scale folded into Wq (exact, 2^-3).
// x staged to wave-private LDS (8KB/block) between QK and V phases.

typedef __attribute__((ext_vector_type(8))) short bf16x8;
typedef __attribute__((ext_vector_type(4))) short bf16x4;
typedef __attribute__((ext_vector_type(4))) float f32x4;

#define MFMA32(a, b, c) __builtin_amdgcn_mfma_f32_16x16x32_bf16(a, b, c, 0, 0, 0)
#define LOG2E 1.44269504088896f

__device__ __forceinline__ unsigned short f2b(float f) {
    return __builtin_bit_cast(unsigned short, __float2bfloat16(f));   // RNE
}

__device__ __forceinline__ bf16x4 pack4(f32x4 a, float s) {
    bf16x4 r;
    r[0] = (short)f2b(a[0] * s); r[1] = (short)f2b(a[1] * s);
    r[2] = (short)f2b(a[2] * s); r[3] = (short)f2b(a[3] * s);
    return r;
}

__device__ __forceinline__ bf16x4 zero4() {
    bf16x4 r; r[0] = 0; r[1] = 0; r[2] = 0; r[3] = 0; return r;
}

__device__ __forceinline__ bf16x8 cat(bf16x4 lo, bf16x4 hi) {
    bf16x8 r;
    r[0] = lo[0]; r[1] = lo[1]; r[2] = lo[2]; r[3] = lo[3];
    r[4] = hi[0]; r[5] = hi[1]; r[6] = hi[2]; r[7] = hi[3];
    return r;
}

__device__ __forceinline__ bf16x8 cvt8(float4 a, float4 b) {
    bf16x8 r;
    r[0] = (short)f2b(a.x); r[1] = (short)f2b(a.y);
    r[2] = (short)f2b(a.z); r[3] = (short)f2b(a.w);
    r[4] = (short)f2b(b.x); r[5] = (short)f2b(b.y);
    r[6] = (short)f2b(b.z); r[7] = (short)f2b(b.w);
    return r;
}

// ---- pre-kernel: convert weights fp32 -> bf16 into d_ws; Wq scaled by 1/8 ----
__global__ void cvt_w_kernel(const float* __restrict__ wk, const float* __restrict__ wq,
                             const float* __restrict__ wv, const float* __restrict__ wp,
                             unsigned short* __restrict__ dst) {
    int e = blockIdx.x * 256 + threadIdx.x;   // 0..16383
    int m = e >> 12;
    int off = e & 4095;
    const float* src = (m == 0) ? wk : (m == 1) ? wq : (m == 2) ? wv : wp;
    float s = (m == 1) ? 0.125f : 1.0f;       // 2^-3: exact in bf16
    dst[e] = f2b(src[off] * s);
}

__global__ __launch_bounds__(64, 4) void attn_fused_kernel(
    const float* __restrict__ x,              // [4096,64,64] fp32
    const unsigned short* __restrict__ wbf,   // bf16: Wk, Wq(/8), Wv, Wp
    const float* __restrict__ bp,             // [64] fp32
    float* __restrict__ out)                  // [4096,64,64] fp32
{
    __shared__ short xls[8 * 64 * 8];         // 8 KB, wave-private

    const int lane = threadIdx.x;             // 0..63
    const int r = lane & 15;      // frag col / A-row
    const int g = lane >> 4;      // lane group: D rows g*4+j; K32 k = g*8+e
    const long b = blockIdx.x;

    const float* xb = x + b * 4096;
    const unsigned short* Wk = wbf;
    const unsigned short* Wq = wbf + 4096;
    const unsigned short* Wv = wbf + 8192;
    const unsigned short* Wp = wbf + 12288;

    // ---- phase 1: load x, convert, stash to LDS ----
    bf16x8 xf[8];                             // frag f: t=(f>>1)*16+r, c=(f&1)*32+g*8..
    #pragma unroll
    for (int f = 0; f < 8; ++f) {
        const float* p = xb + ((f >> 1) * 16 + r) * 64 + (f & 1) * 32 + g * 8;
        xf[f] = cvt8(*(const float4*)p, *(const float4*)(p + 4));
    }
    #pragma unroll
    for (int f = 0; f < 8; ++f)
        *(bf16x8*)(xls + (f * 64 + lane) * 8) = xf[f];

    // ---- phase 2: kT = Wk @ xT (weights streamed 2 frags at a time) ----
    bf16x8 kT8[2][4];
    #pragma unroll
    for (int cm2 = 0; cm2 < 2; ++cm2) {
        bf16x4 lo[4];
        #pragma unroll
        for (int h = 0; h < 2; ++h) {
            const int cm = cm2 * 2 + h;
            bf16x8 a0 = *(const bf16x8*)(Wk + (cm * 16 + r) * 64 + g * 8);
            bf16x8 a1 = *(const bf16x8*)(Wk + (cm * 16 + r) * 64 + 32 + g * 8);
            #pragma unroll
            for (int sm = 0; sm < 4; ++sm) {
                f32x4 acc = {0.f, 0.f, 0.f, 0.f};
                acc = MFMA32(a0, xf[sm * 2], acc);
                acc = MFMA32(a1, xf[sm * 2 + 1], acc);
                if (h == 0) lo[sm] = pack4(acc, 1.0f);
                else kT8[cm2][sm] = cat(lo[sm], pack4(acc, 1.0f));
            }
        }
    }

    // ---- phase 3: qT = (Wq/8) @ xT -> q8 regs ----
    bf16x8 q8[2][4];
    #pragma unroll
    for (int cm2 = 0; cm2 < 2; ++cm2) {
        bf16x4 lo[4];
        #pragma unroll
        for (int h = 0; h < 2; ++h) {
            const int cm = cm2 * 2 + h;
            bf16x8 a0 = *(const bf16x8*)(Wq + (cm * 16 + r) * 64 + g * 8);
            bf16x8 a1 = *(const bf16x8*)(Wq + (cm * 16 + r) * 64 + 32 + g * 8);
            #pragma unroll
            for (int tt = 0; tt < 4; ++tt) {
                f32x4 acc = {0.f, 0.f, 0.f, 0.f};
                acc = MFMA32(a0, xf[tt * 2], acc);
                acc = MFMA32(a1, xf[tt * 2 + 1], acc);
                if (h == 0) lo[tt] = pack4(acc, 1.0f);
                else q8[cm2][tt] = cat(lo[tt], pack4(acc, 1.0f));
            }
        }
    }
    // xf dead (x lives in LDS).

    // ---- phase 4: scores + softmax for ALL column tiles -> P ----
    // per lane: column t = tn*16+r, rows s = sm*16 + g*4 + j
    bf16x4 P[4][4];                           // [sm][tn]; sm>tn slots zero
    #pragma unroll
    for (int tn = 0; tn < 4; ++tn) {
        f32x4 st[4];
        #pragma unroll
        for (int sm = 0; sm < 4; ++sm) {
            if (sm > tn) continue;
            f32x4 acc = {0.f, 0.f, 0.f, 0.f};
            acc = MFMA32(kT8[0][sm], q8[0][tn], acc);
            acc = MFMA32(kT8[1][sm], q8[1][tn], acc);
            st[sm] = acc;
        }
        float mx = -1e30f;
        #pragma unroll
        for (int sm = 0; sm < 4; ++sm) {
            if (sm > tn) continue;
            #pragma unroll
            for (int j = 0; j < 4; ++j) {
                float v = st[sm][j];
                if (sm == tn) v = ((g * 4 + j) <= r) ? v : -1e30f;  // causal
                st[sm][j] = v;
                mx = fmaxf(mx, v);
            }
        }
        mx = fmaxf(mx, __shfl_xor(mx, 16));
        mx = fmaxf(mx, __shfl_xor(mx, 32));
        float sum = 0.f;
        #pragma unroll
        for (int sm = 0; sm < 4; ++sm) {
            if (sm > tn) continue;
            #pragma unroll
            for (int j = 0; j < 4; ++j) {
                float e = exp2f((st[sm][j] - mx) * LOG2E);
                st[sm][j] = e;
                sum += e;
            }
        }
        sum += __shfl_xor(sum, 16);
        sum += __shfl_xor(sum, 32);
        float inv = __builtin_amdgcn_rcpf(sum);   // sum >= 1 (diagonal present)
        #pragma unroll
        for (int sm = 0; sm < 4; ++sm)
            P[sm][tn] = (sm <= tn) ? pack4(st[sm], inv) : zero4();
    }
    // kT8, q8 dead.

    // ---- phase 5: v = x @ WvT (x from LDS, Wv streamed) ----
    bf16x8 xv[8];
    #pragma unroll
    for (int f = 0; f < 8; ++f)
        xv[f] = *(const bf16x8*)(xls + (f * 64 + lane) * 8);
    bf16x8 v8[4][2];
    #pragma unroll
    for (int cm = 0; cm < 4; ++cm) {
        bf16x8 b0 = *(const bf16x8*)(Wv + (cm * 16 + r) * 64 + g * 8);
        bf16x8 b1 = *(const bf16x8*)(Wv + (cm * 16 + r) * 64 + 32 + g * 8);
        bf16x4 tmp[4];
        #pragma unroll
        for (int tv = 0; tv < 4; ++tv) {
            f32x4 acc = {0.f, 0.f, 0.f, 0.f};
            acc = MFMA32(xv[tv * 2], b0, acc);
            acc = MFMA32(xv[tv * 2 + 1], b1, acc);
            tmp[tv] = pack4(acc, 1.0f);
        }
        v8[cm][0] = cat(tmp[0], tmp[1]);
        v8[cm][1] = cat(tmp[2], tmp[3]);
    }
    // xv dead.

    // ---- phase 6: out2T = v * PT for all tiles -> o28 ----
    bf16x8 o28[4][2];                         // [tn][cm2]
    #pragma unroll
    for (int tn = 0; tn < 4; ++tn) {
        bf16x8 pt80 = cat(P[0][tn], P[1][tn]);
        bf16x8 pt81 = cat(P[2][tn], P[3][tn]);
        bf16x4 c[4];
        #pragma unroll
        for (int cm = 0; cm < 4; ++cm) {
            f32x4 acc = {0.f, 0.f, 0.f, 0.f};
            acc = MFMA32(v8[cm][0], pt80, acc);
            if (tn >= 2) acc = MFMA32(v8[cm][1], pt81, acc);
            c[cm] = pack4(acc, 1.0f);
        }
        o28[tn][0] = cat(c[0], c[1]);
        o28[tn][1] = cat(c[2], c[3]);
    }
    // P, v8 dead.

    // ---- phase 7: resT = Wp @ out2T + bias -> global ----
    float* ob = out + b * 4096;
    #pragma unroll
    for (int om = 0; om < 4; ++om) {
        const unsigned short* wrow = Wp + (om * 16 + r) * 64 + g * 4;
        bf16x8 w0 = cat(*(const bf16x4*)(wrow),      *(const bf16x4*)(wrow + 16));
        bf16x8 w1 = cat(*(const bf16x4*)(wrow + 32), *(const bf16x4*)(wrow + 48));
        const float4 bias = *(const float4*)(bp + om * 16 + g * 4);
        #pragma unroll
        for (int tn = 0; tn < 4; ++tn) {
            f32x4 acc = {0.f, 0.f, 0.f, 0.f};
            acc = MFMA32(w0, o28[tn][0], acc);
            acc = MFMA32(w1, o28[tn][1], acc);
            float4 o;
            o.x = acc[0] + bias.x; o.y = acc[1] + bias.y;
            o.z = acc[2] + bias.z; o.w = acc[3] + bias.w;
            *(float4*)(ob + (tn * 16 + r) * 64 + om * 16 + g * 4) = o;
        }
    }
}

extern "C" void kernel_launch(void* const* d_in, const int* in_sizes, int n_in,
                              void* d_out, int out_size, void* d_ws, size_t ws_size,
                              hipStream_t stream) {
    const float* x  = (const float*)d_in[0];
    const float* wk = (const float*)d_in[1];
    const float* wq = (const float*)d_in[2];
    const float* wv = (const float*)d_in[3];
    const float* wp = (const float*)d_in[4];
    const float* bp = (const float*)d_in[5];
    unsigned short* wbf = (unsigned short*)d_ws;   // 16384 bf16 = 32 KB

    cvt_w_kernel<<<64, 256, 0, stream>>>(wk, wq, wv, wp, wbf);
    attn_fused_kernel<<<4096, 64, 0, stream>>>(x, wbf, bp, (float*)d_out);
}

// Round 8
// 40.228 us; speedup vs baseline: 1.5061x; 1.1952x over previous
//
#include <hip/hip_runtime.h>
#include <hip/hip_bf16.h>

// Fused causal self-attention: B=4096 independent (T=64, C=64) problems.
// ONE WAVE per batch, 4 waves (4 batches) per 256-thread block, 1024 blocks
// (= 4 blocks/CU exactly). All 4 weight matrices staged ONCE per block into
// LDS (32 KB, bf16, XOR-swizzled vs the 128B-row-stride bank conflict), so
// every weight fragment read is a short-latency ds_read instead of a ~300cy
// L2 gather. x lives in registers end-to-end. One barrier (after staging).
// All matmuls v_mfma_f32_16x16x32_bf16; K=16 D-frags paired into K=32.
// Softmax: __shfl_xor lane bits 4,5 (proven). 1/8 folded into Wq (exact).

typedef __attribute__((ext_vector_type(8))) short bf16x8;
typedef __attribute__((ext_vector_type(4))) short bf16x4;
typedef __attribute__((ext_vector_type(4))) float f32x4;

#define MFMA32(a, b, c) __builtin_amdgcn_mfma_f32_16x16x32_bf16(a, b, c, 0, 0, 0)
#define LOG2E 1.44269504088896f

__device__ __forceinline__ unsigned short f2b(float f) {
    return __builtin_bit_cast(unsigned short, __float2bfloat16(f));   // RNE
}

__device__ __forceinline__ bf16x4 pack4(f32x4 a, float s) {
    bf16x4 r;
    r[0] = (short)f2b(a[0] * s); r[1] = (short)f2b(a[1] * s);
    r[2] = (short)f2b(a[2] * s); r[3] = (short)f2b(a[3] * s);
    return r;
}

__device__ __forceinline__ bf16x4 zero4() {
    bf16x4 r; r[0] = 0; r[1] = 0; r[2] = 0; r[3] = 0; return r;
}

__device__ __forceinline__ bf16x8 cat(bf16x4 lo, bf16x4 hi) {
    bf16x8 r;
    r[0] = lo[0]; r[1] = lo[1]; r[2] = lo[2]; r[3] = lo[3];
    r[4] = hi[0]; r[5] = hi[1]; r[6] = hi[2]; r[7] = hi[3];
    return r;
}

__device__ __forceinline__ bf16x8 cvt8(float4 a, float4 b) {
    bf16x8 r;
    r[0] = (short)f2b(a.x); r[1] = (short)f2b(a.y);
    r[2] = (short)f2b(a.z); r[3] = (short)f2b(a.w);
    r[4] = (short)f2b(b.x); r[5] = (short)f2b(b.y);
    r[6] = (short)f2b(b.z); r[7] = (short)f2b(b.w);
    return r;
}

// LDS weight addressing: matrices concatenated [4][64][64] bf16, row = 128 B.
// XOR swizzle (T2 / G4): byte ^= (row&7)<<4  ->  elem col ^= (row&7)<<3.
// Row-major reads by 64 lanes at fixed col spread across 8 16B slots.
__device__ __forceinline__ int swz(int row, int col) {
    return row * 64 + (col ^ ((row & 7) << 3));
}

// ---- pre-kernel: convert weights fp32 -> bf16 into d_ws; Wq scaled by 1/8 ----
__global__ void cvt_w_kernel(const float* __restrict__ wk, const float* __restrict__ wq,
                             const float* __restrict__ wv, const float* __restrict__ wp,
                             unsigned short* __restrict__ dst) {
    int e = blockIdx.x * 256 + threadIdx.x;   // 0..16383
    int m = e >> 12;
    int off = e & 4095;
    const float* src = (m == 0) ? wk : (m == 1) ? wq : (m == 2) ? wv : wp;
    float s = (m == 1) ? 0.125f : 1.0f;       // 2^-3: exact in bf16
    dst[e] = f2b(src[off] * s);
}

__global__ __launch_bounds__(256, 4) void attn_fused_kernel(
    const float* __restrict__ x,              // [4096,64,64] fp32
    const unsigned short* __restrict__ wbf,   // bf16: Wk, Wq(/8), Wv, Wp
    const float* __restrict__ bp,             // [64] fp32
    float* __restrict__ out)                  // [4096,64,64] fp32
{
    __shared__ short lw[16384];               // 32 KB: all 4 weight matrices, swizzled

    const int tid  = threadIdx.x;
    const int wv_  = tid >> 6;
    const int lane = tid & 63;
    const int r = lane & 15;      // frag col / A-row
    const int g = lane >> 4;      // lane group: D rows g*4+j; K32 k = g*8+e
    const long b = (long)blockIdx.x * 4 + wv_;
    const float* xb = x + b * 4096;

    // ---- phase 0: issue x loads (16 x float4, coalesced) ----
    float4 raw[8][2];
    #pragma unroll
    for (int f = 0; f < 8; ++f) {
        const float* p = xb + ((f >> 1) * 16 + r) * 64 + (f & 1) * 32 + g * 8;
        raw[f][0] = *(const float4*)p;
        raw[f][1] = *(const float4*)(p + 4);
    }

    // ---- stage all weights to LDS (swizzled), 128 B per thread ----
    {
        const int rw = tid;                   // global row 0..255 ([4][64] rows)
        #pragma unroll
        for (int i = 0; i < 8; ++i) {
            bf16x8 v = *(const bf16x8*)(wbf + rw * 64 + i * 8);
            *(bf16x8*)(lw + rw * 64 + ((i ^ (rw & 7)) * 8)) = v;
        }
    }

    // ---- convert x to bf16 frags (regs, held through scores) ----
    bf16x8 xf[8];                             // frag f: t=(f>>1)*16+r, c=(f&1)*32+g*8..
    #pragma unroll
    for (int f = 0; f < 8; ++f)
        xf[f] = cvt8(raw[f][0], raw[f][1]);

    __syncthreads();                          // weights visible to all waves

    const short* Wk = lw;
    const short* Wq = lw + 4096;
    const short* Wv = lw + 8192;
    const short* Wp = lw + 12288;

    // ---- kT = Wk @ xT -> kT8[cm2][sm] ----
    bf16x8 kT8[2][4];
    #pragma unroll
    for (int cm2 = 0; cm2 < 2; ++cm2) {
        bf16x4 lo[4];
        #pragma unroll
        for (int h = 0; h < 2; ++h) {
            const int cm = cm2 * 2 + h;
            bf16x8 a0 = *(const bf16x8*)(Wk + swz(cm * 16 + r, g * 8));
            bf16x8 a1 = *(const bf16x8*)(Wk + swz(cm * 16 + r, 32 + g * 8));
            #pragma unroll
            for (int sm = 0; sm < 4; ++sm) {
                f32x4 acc = {0.f, 0.f, 0.f, 0.f};
                acc = MFMA32(a0, xf[sm * 2], acc);
                acc = MFMA32(a1, xf[sm * 2 + 1], acc);
                if (h == 0) lo[sm] = pack4(acc, 1.0f);
                else kT8[cm2][sm] = cat(lo[sm], pack4(acc, 1.0f));
            }
        }
    }

    // ---- qT = (Wq/8) @ xT -> q8[cm2][tt] ----
    bf16x8 q8[2][4];
    #pragma unroll
    for (int cm2 = 0; cm2 < 2; ++cm2) {
        bf16x4 lo[4];
        #pragma unroll
        for (int h = 0; h < 2; ++h) {
            const int cm = cm2 * 2 + h;
            bf16x8 a0 = *(const bf16x8*)(Wq + swz(cm * 16 + r, g * 8));
            bf16x8 a1 = *(const bf16x8*)(Wq + swz(cm * 16 + r, 32 + g * 8));
            #pragma unroll
            for (int tt = 0; tt < 4; ++tt) {
                f32x4 acc = {0.f, 0.f, 0.f, 0.f};
                acc = MFMA32(a0, xf[tt * 2], acc);
                acc = MFMA32(a1, xf[tt * 2 + 1], acc);
                if (h == 0) lo[tt] = pack4(acc, 1.0f);
                else q8[cm2][tt] = cat(lo[tt], pack4(acc, 1.0f));
            }
        }
    }

    // ---- scores + softmax for ALL column tiles -> P ----
    // per lane: column t = tn*16+r, rows s = sm*16 + g*4 + j
    bf16x4 P[4][4];                           // [sm][tn]; sm>tn slots zero
    #pragma unroll
    for (int tn = 0; tn < 4; ++tn) {
        f32x4 st[4];
        #pragma unroll
        for (int sm = 0; sm < 4; ++sm) {
            if (sm > tn) continue;
            f32x4 acc = {0.f, 0.f, 0.f, 0.f};
            acc = MFMA32(kT8[0][sm], q8[0][tn], acc);
            acc = MFMA32(kT8[1][sm], q8[1][tn], acc);
            st[sm] = acc;
        }
        float mx = -1e30f;
        #pragma unroll
        for (int sm = 0; sm < 4; ++sm) {
            if (sm > tn) continue;
            #pragma unroll
            for (int j = 0; j < 4; ++j) {
                float v = st[sm][j];
                if (sm == tn) v = ((g * 4 + j) <= r) ? v : -1e30f;  // causal
                st[sm][j] = v;
                mx = fmaxf(mx, v);
            }
        }
        mx = fmaxf(mx, __shfl_xor(mx, 16));
        mx = fmaxf(mx, __shfl_xor(mx, 32));
        float sum = 0.f;
        #pragma unroll
        for (int sm = 0; sm < 4; ++sm) {
            if (sm > tn) continue;
            #pragma unroll
            for (int j = 0; j < 4; ++j) {
                float e = exp2f((st[sm][j] - mx) * LOG2E);
                st[sm][j] = e;
                sum += e;
            }
        }
        sum += __shfl_xor(sum, 16);
        sum += __shfl_xor(sum, 32);
        float inv = __builtin_amdgcn_rcpf(sum);   // sum >= 1 (diagonal present)
        #pragma unroll
        for (int sm = 0; sm < 4; ++sm)
            P[sm][tn] = (sm <= tn) ? pack4(st[sm], inv) : zero4();
    }
    // kT8, q8 dead.

    // ---- v = x @ WvT (x still in regs, Wv from LDS) -> v8[cm][sm2] ----
    bf16x8 v8[4][2];
    #pragma unroll
    for (int cm = 0; cm < 4; ++cm) {
        bf16x8 b0 = *(const bf16x8*)(Wv + swz(cm * 16 + r, g * 8));
        bf16x8 b1 = *(const bf16x8*)(Wv + swz(cm * 16 + r, 32 + g * 8));
        bf16x4 tmp[4];
        #pragma unroll
        for (int tv = 0; tv < 4; ++tv) {
            f32x4 acc = {0.f, 0.f, 0.f, 0.f};
            acc = MFMA32(xf[tv * 2], b0, acc);
            acc = MFMA32(xf[tv * 2 + 1], b1, acc);
            tmp[tv] = pack4(acc, 1.0f);
        }
        v8[cm][0] = cat(tmp[0], tmp[1]);
        v8[cm][1] = cat(tmp[2], tmp[3]);
    }
    // xf dead.

    // ---- out2T = v * PT for all tiles -> o28[tn][cm2] ----
    bf16x8 o28[4][2];
    #pragma unroll
    for (int tn = 0; tn < 4; ++tn) {
        bf16x8 pt80 = cat(P[0][tn], P[1][tn]);
        bf16x8 pt81 = cat(P[2][tn], P[3][tn]);
        bf16x4 c[4];
        #pragma unroll
        for (int cm = 0; cm < 4; ++cm) {
            f32x4 acc = {0.f, 0.f, 0.f, 0.f};
            acc = MFMA32(v8[cm][0], pt80, acc);
            if (tn >= 2) acc = MFMA32(v8[cm][1], pt81, acc);
            c[cm] = pack4(acc, 1.0f);
        }
        o28[tn][0] = cat(c[0], c[1]);
        o28[tn][1] = cat(c[2], c[3]);
    }
    // P, v8 dead.

    // ---- resT = Wp @ out2T + bias -> global ----
    float* ob = out + b * 4096;
    #pragma unroll
    for (int om = 0; om < 4; ++om) {
        bf16x8 w0 = cat(*(const bf16x4*)(Wp + swz(om * 16 + r, g * 4)),
                        *(const bf16x4*)(Wp + swz(om * 16 + r, 16 + g * 4)));
        bf16x8 w1 = cat(*(const bf16x4*)(Wp + swz(om * 16 + r, 32 + g * 4)),
                        *(const bf16x4*)(Wp + swz(om * 16 + r, 48 + g * 4)));
        const float4 bias = *(const float4*)(bp + om * 16 + g * 4);
        #pragma unroll
        for (int tn = 0; tn < 4; ++tn) {
            f32x4 acc = {0.f, 0.f, 0.f, 0.f};
            acc = MFMA32(w0, o28[tn][0], acc);
            acc = MFMA32(w1, o28[tn][1], acc);
            float4 o;
            o.x = acc[0] + bias.x; o.y = acc[1] + bias.y;
            o.z = acc[2] + bias.z; o.w = acc[3] + bias.w;
            *(float4*)(ob + (tn * 16 + r) * 64 + om * 16 + g * 4) = o;
        }
    }
}

extern "C" void kernel_launch(void* const* d_in, const int* in_sizes, int n_in,
                              void* d_out, int out_size, void* d_ws, size_t ws_size,
                              hipStream_t stream) {
    const float* x  = (const float*)d_in[0];
    const float* wk = (const float*)d_in[1];
    const float* wq = (const float*)d_in[2];
    const float* wv = (const float*)d_in[3];
    const float* wp = (const float*)d_in[4];
    const float* bp = (const float*)d_in[5];
    unsigned short* wbf = (unsigned short*)d_ws;   // 16384 bf16 = 32 KB

    cvt_w_kernel<<<64, 256, 0, stream>>>(wk, wq, wv, wp, wbf);
    attn_fused_kernel<<<1024, 256, 0, stream>>>(x, wbf, bp, (float*)d_out);
}

// Round 9
// 39.182 us; speedup vs baseline: 1.5463x; 1.0267x over previous
//
#include <hip/hip_runtime.h>
#include <hip/hip_bf16.h>

// Fused causal self-attention: B=4096 independent (T=64, C=64) problems.
// R9: anti-lockstep pipelining. 512 blocks x 4 waves; each wave processes TWO
// batches (b, b+2048) sequentially. Batch-2's x loads are issued right after
// the staging barrier and fly under batch-1's whole compute; batch-1's stores
// drain under batch-2's compute. No barriers inside the loop -> waves drift,
// spreading HBM read/write traffic across the kernel instead of bursting.
// Weights staged once to LDS (32 KB, XOR-swizzled). All matmuls
// v_mfma_f32_16x16x32_bf16; softmax via __shfl_xor (proven); 1/8 in Wq.

typedef __attribute__((ext_vector_type(8))) short bf16x8;
typedef __attribute__((ext_vector_type(4))) short bf16x4;
typedef __attribute__((ext_vector_type(4))) float f32x4;

#define MFMA32(a, b, c) __builtin_amdgcn_mfma_f32_16x16x32_bf16(a, b, c, 0, 0, 0)
#define LOG2E 1.44269504088896f

__device__ __forceinline__ unsigned short f2b(float f) {
    return __builtin_bit_cast(unsigned short, __float2bfloat16(f));   // RNE
}

__device__ __forceinline__ bf16x4 pack4(f32x4 a, float s) {
    bf16x4 r;
    r[0] = (short)f2b(a[0] * s); r[1] = (short)f2b(a[1] * s);
    r[2] = (short)f2b(a[2] * s); r[3] = (short)f2b(a[3] * s);
    return r;
}

__device__ __forceinline__ bf16x4 zero4() {
    bf16x4 r; r[0] = 0; r[1] = 0; r[2] = 0; r[3] = 0; return r;
}

__device__ __forceinline__ bf16x8 cat(bf16x4 lo, bf16x4 hi) {
    bf16x8 r;
    r[0] = lo[0]; r[1] = lo[1]; r[2] = lo[2]; r[3] = lo[3];
    r[4] = hi[0]; r[5] = hi[1]; r[6] = hi[2]; r[7] = hi[3];
    return r;
}

__device__ __forceinline__ bf16x8 cvt8(float4 a, float4 b) {
    bf16x8 r;
    r[0] = (short)f2b(a.x); r[1] = (short)f2b(a.y);
    r[2] = (short)f2b(a.z); r[3] = (short)f2b(a.w);
    r[4] = (short)f2b(b.x); r[5] = (short)f2b(b.y);
    r[6] = (short)f2b(b.z); r[7] = (short)f2b(b.w);
    return r;
}

// LDS weight addressing: [4][64][64] bf16, row = 128 B.
// XOR swizzle: elem col ^= (row&7)<<3 (byte ^= (row&7)<<4).
__device__ __forceinline__ int swz(int row, int col) {
    return row * 64 + (col ^ ((row & 7) << 3));
}

// ---- pre-kernel: convert weights fp32 -> bf16 into d_ws; Wq scaled by 1/8 ----
__global__ void cvt_w_kernel(const float* __restrict__ wk, const float* __restrict__ wq,
                             const float* __restrict__ wv, const float* __restrict__ wp,
                             unsigned short* __restrict__ dst) {
    int e = blockIdx.x * 256 + threadIdx.x;   // 0..16383
    int m = e >> 12;
    int off = e & 4095;
    const float* src = (m == 0) ? wk : (m == 1) ? wq : (m == 2) ? wv : wp;
    float s = (m == 1) ? 0.125f : 1.0f;       // 2^-3: exact in bf16
    dst[e] = f2b(src[off] * s);
}

// One full batch: K,Q,scores+softmax,V,PV,projection+store. xf in regs.
__device__ __forceinline__ void compute_batch(
    const short* __restrict__ lw, const bf16x8 xf[8],
    const float* __restrict__ bp, float* __restrict__ ob, int r, int g)
{
    const short* Wk = lw;
    const short* Wq = lw + 4096;
    const short* Wv = lw + 8192;
    const short* Wp = lw + 12288;

    // kT = Wk @ xT
    bf16x8 kT8[2][4];
    #pragma unroll
    for (int cm2 = 0; cm2 < 2; ++cm2) {
        bf16x4 lo[4];
        #pragma unroll
        for (int h = 0; h < 2; ++h) {
            const int cm = cm2 * 2 + h;
            bf16x8 a0 = *(const bf16x8*)(Wk + swz(cm * 16 + r, g * 8));
            bf16x8 a1 = *(const bf16x8*)(Wk + swz(cm * 16 + r, 32 + g * 8));
            #pragma unroll
            for (int sm = 0; sm < 4; ++sm) {
                f32x4 acc = {0.f, 0.f, 0.f, 0.f};
                acc = MFMA32(a0, xf[sm * 2], acc);
                acc = MFMA32(a1, xf[sm * 2 + 1], acc);
                if (h == 0) lo[sm] = pack4(acc, 1.0f);
                else kT8[cm2][sm] = cat(lo[sm], pack4(acc, 1.0f));
            }
        }
    }

    // qT = (Wq/8) @ xT
    bf16x8 q8[2][4];
    #pragma unroll
    for (int cm2 = 0; cm2 < 2; ++cm2) {
        bf16x4 lo[4];
        #pragma unroll
        for (int h = 0; h < 2; ++h) {
            const int cm = cm2 * 2 + h;
            bf16x8 a0 = *(const bf16x8*)(Wq + swz(cm * 16 + r, g * 8));
            bf16x8 a1 = *(const bf16x8*)(Wq + swz(cm * 16 + r, 32 + g * 8));
            #pragma unroll
            for (int tt = 0; tt < 4; ++tt) {
                f32x4 acc = {0.f, 0.f, 0.f, 0.f};
                acc = MFMA32(a0, xf[tt * 2], acc);
                acc = MFMA32(a1, xf[tt * 2 + 1], acc);
                if (h == 0) lo[tt] = pack4(acc, 1.0f);
                else q8[cm2][tt] = cat(lo[tt], pack4(acc, 1.0f));
            }
        }
    }

    // scores + softmax -> P  (lane: col t = tn*16+r, rows s = sm*16+g*4+j)
    bf16x4 P[4][4];
    #pragma unroll
    for (int tn = 0; tn < 4; ++tn) {
        f32x4 st[4];
        #pragma unroll
        for (int sm = 0; sm < 4; ++sm) {
            if (sm > tn) continue;
            f32x4 acc = {0.f, 0.f, 0.f, 0.f};
            acc = MFMA32(kT8[0][sm], q8[0][tn], acc);
            acc = MFMA32(kT8[1][sm], q8[1][tn], acc);
            st[sm] = acc;
        }
        float mx = -1e30f;
        #pragma unroll
        for (int sm = 0; sm < 4; ++sm) {
            if (sm > tn) continue;
            #pragma unroll
            for (int j = 0; j < 4; ++j) {
                float v = st[sm][j];
                if (sm == tn) v = ((g * 4 + j) <= r) ? v : -1e30f;  // causal
                st[sm][j] = v;
                mx = fmaxf(mx, v);
            }
        }
        mx = fmaxf(mx, __shfl_xor(mx, 16));
        mx = fmaxf(mx, __shfl_xor(mx, 32));
        float sum = 0.f;
        #pragma unroll
        for (int sm = 0; sm < 4; ++sm) {
            if (sm > tn) continue;
            #pragma unroll
            for (int j = 0; j < 4; ++j) {
                float e = exp2f((st[sm][j] - mx) * LOG2E);
                st[sm][j] = e;
                sum += e;
            }
        }
        sum += __shfl_xor(sum, 16);
        sum += __shfl_xor(sum, 32);
        float inv = __builtin_amdgcn_rcpf(sum);   // sum >= 1 (diagonal present)
        #pragma unroll
        for (int sm = 0; sm < 4; ++sm)
            P[sm][tn] = (sm <= tn) ? pack4(st[sm], inv) : zero4();
    }

    // v = x @ WvT
    bf16x8 v8[4][2];
    #pragma unroll
    for (int cm = 0; cm < 4; ++cm) {
        bf16x8 b0 = *(const bf16x8*)(Wv + swz(cm * 16 + r, g * 8));
        bf16x8 b1 = *(const bf16x8*)(Wv + swz(cm * 16 + r, 32 + g * 8));
        bf16x4 tmp[4];
        #pragma unroll
        for (int tv = 0; tv < 4; ++tv) {
            f32x4 acc = {0.f, 0.f, 0.f, 0.f};
            acc = MFMA32(xf[tv * 2], b0, acc);
            acc = MFMA32(xf[tv * 2 + 1], b1, acc);
            tmp[tv] = pack4(acc, 1.0f);
        }
        v8[cm][0] = cat(tmp[0], tmp[1]);
        v8[cm][1] = cat(tmp[2], tmp[3]);
    }

    // out2T = v * PT
    bf16x8 o28[4][2];
    #pragma unroll
    for (int tn = 0; tn < 4; ++tn) {
        bf16x8 pt80 = cat(P[0][tn], P[1][tn]);
        bf16x8 pt81 = cat(P[2][tn], P[3][tn]);
        bf16x4 c[4];
        #pragma unroll
        for (int cm = 0; cm < 4; ++cm) {
            f32x4 acc = {0.f, 0.f, 0.f, 0.f};
            acc = MFMA32(v8[cm][0], pt80, acc);
            if (tn >= 2) acc = MFMA32(v8[cm][1], pt81, acc);
            c[cm] = pack4(acc, 1.0f);
        }
        o28[tn][0] = cat(c[0], c[1]);
        o28[tn][1] = cat(c[2], c[3]);
    }

    // resT = Wp @ out2T + bias -> global
    #pragma unroll
    for (int om = 0; om < 4; ++om) {
        bf16x8 w0 = cat(*(const bf16x4*)(Wp + swz(om * 16 + r, g * 4)),
                        *(const bf16x4*)(Wp + swz(om * 16 + r, 16 + g * 4)));
        bf16x8 w1 = cat(*(const bf16x4*)(Wp + swz(om * 16 + r, 32 + g * 4)),
                        *(const bf16x4*)(Wp + swz(om * 16 + r, 48 + g * 4)));
        const float4 bias = *(const float4*)(bp + om * 16 + g * 4);
        #pragma unroll
        for (int tn = 0; tn < 4; ++tn) {
            f32x4 acc = {0.f, 0.f, 0.f, 0.f};
            acc = MFMA32(w0, o28[tn][0], acc);
            acc = MFMA32(w1, o28[tn][1], acc);
            float4 o;
            o.x = acc[0] + bias.x; o.y = acc[1] + bias.y;
            o.z = acc[2] + bias.z; o.w = acc[3] + bias.w;
            *(float4*)(ob + (tn * 16 + r) * 64 + om * 16 + g * 4) = o;
        }
    }
}

__global__ __launch_bounds__(256, 2) void attn_fused_kernel(
    const float* __restrict__ x,              // [4096,64,64] fp32
    const unsigned short* __restrict__ wbf,   // bf16: Wk, Wq(/8), Wv, Wp
    const float* __restrict__ bp,             // [64] fp32
    float* __restrict__ out)                  // [4096,64,64] fp32
{
    __shared__ short lw[16384];               // 32 KB: weights, swizzled

    const int tid  = threadIdx.x;
    const int wv_  = tid >> 6;
    const int lane = tid & 63;
    const int r = lane & 15;
    const int g = lane >> 4;
    const long b0 = (long)blockIdx.x * 4 + wv_;     // [0, 2048)
    const long b1 = b0 + 2048;

    // ---- issue batch-0 x loads ----
    const float* xb0 = x + b0 * 4096;
    float4 raw[8][2];
    #pragma unroll
    for (int f = 0; f < 8; ++f) {
        const float* p = xb0 + ((f >> 1) * 16 + r) * 64 + (f & 1) * 32 + g * 8;
        raw[f][0] = *(const float4*)p;
        raw[f][1] = *(const float4*)(p + 4);
    }

    // ---- stage weights to LDS (swizzled), 128 B per thread ----
    {
        const int rw = tid;
        #pragma unroll
        for (int i = 0; i < 8; ++i) {
            bf16x8 v = *(const bf16x8*)(wbf + rw * 64 + i * 8);
            *(bf16x8*)(lw + rw * 64 + ((i ^ (rw & 7)) * 8)) = v;
        }
    }

    // ---- convert batch-0 x to bf16 frags ----
    bf16x8 xf[8];
    #pragma unroll
    for (int f = 0; f < 8; ++f)
        xf[f] = cvt8(raw[f][0], raw[f][1]);

    __syncthreads();                          // weights visible (drains vmem too)

    // ---- PREFETCH batch-1 x now: flies under batch-0's whole compute ----
    const float* xb1 = x + b1 * 4096;
    float4 raw1[8][2];
    #pragma unroll
    for (int f = 0; f < 8; ++f) {
        const float* p = xb1 + ((f >> 1) * 16 + r) * 64 + (f & 1) * 32 + g * 8;
        raw1[f][0] = *(const float4*)p;
        raw1[f][1] = *(const float4*)(p + 4);
    }

    // ---- batch 0: compute + store (stores drain under batch 1) ----
    compute_batch(lw, xf, bp, out + b0 * 4096, r, g);

    // ---- batch 1: convert (waits prefetch), compute + store ----
    bf16x8 xf1[8];
    #pragma unroll
    for (int f = 0; f < 8; ++f)
        xf1[f] = cvt8(raw1[f][0], raw1[f][1]);

    compute_batch(lw, xf1, bp, out + b1 * 4096, r, g);
}

extern "C" void kernel_launch(void* const* d_in, const int* in_sizes, int n_in,
                              void* d_out, int out_size, void* d_ws, size_t ws_size,
                              hipStream_t stream) {
    const float* x  = (const float*)d_in[0];
    const float* wk = (const float*)d_in[1];
    const float* wq = (const float*)d_in[2];
    const float* wv = (const float*)d_in[3];
    const float* wp = (const float*)d_in[4];
    const float* bp = (const float*)d_in[5];
    unsigned short* wbf = (unsigned short*)d_ws;   // 16384 bf16 = 32 KB

    cvt_w_kernel<<<64, 256, 0, stream>>>(wk, wq, wv, wp, wbf);
    attn_fused_kernel<<<512, 256, 0, stream>>>(x, wbf, bp, (float*)d_out);
}

// Round 10
// 32.790 us; speedup vs baseline: 1.8477x; 1.1949x over previous
//
#include <hip/hip_runtime.h>
#include <hip/hip_bf16.h>

// Fused causal self-attention: B=4096 independent (T=64, C=64) problems.
// R10 = R9 (2 batches/wave, prefetch, LDS weights) + COALESCED OUTPUT STORES:
// resT fragments are bounced through a padded wave-private LDS chunk and
// written as 4 x 1KB contiguous wave-stores per 16-row tile (full 128B lines),
// eliminating the 1.55x HBM write amplification of the direct frag stores
// (WRITE_SIZE 99MB for a 64MB output in R2-R9; R1's pattern showed 65.5MB).
// Weights staged once to LDS (32 KB, XOR-swizzled). All matmuls
// v_mfma_f32_16x16x32_bf16; softmax via __shfl_xor; 1/8 folded into Wq.

typedef __attribute__((ext_vector_type(8))) short bf16x8;
typedef __attribute__((ext_vector_type(4))) short bf16x4;
typedef __attribute__((ext_vector_type(4))) float f32x4;

#define MFMA32(a, b, c) __builtin_amdgcn_mfma_f32_16x16x32_bf16(a, b, c, 0, 0, 0)
#define LOG2E 1.44269504088896f
#define BSTR 68   // bounce-buffer row stride in floats (64 + 4: breaks bank alias)

__device__ __forceinline__ unsigned short f2b(float f) {
    return __builtin_bit_cast(unsigned short, __float2bfloat16(f));   // RNE
}

__device__ __forceinline__ bf16x4 pack4(f32x4 a, float s) {
    bf16x4 r;
    r[0] = (short)f2b(a[0] * s); r[1] = (short)f2b(a[1] * s);
    r[2] = (short)f2b(a[2] * s); r[3] = (short)f2b(a[3] * s);
    return r;
}

__device__ __forceinline__ bf16x4 zero4() {
    bf16x4 r; r[0] = 0; r[1] = 0; r[2] = 0; r[3] = 0; return r;
}

__device__ __forceinline__ bf16x8 cat(bf16x4 lo, bf16x4 hi) {
    bf16x8 r;
    r[0] = lo[0]; r[1] = lo[1]; r[2] = lo[2]; r[3] = lo[3];
    r[4] = hi[0]; r[5] = hi[1]; r[6] = hi[2]; r[7] = hi[3];
    return r;
}

__device__ __forceinline__ bf16x8 cvt8(float4 a, float4 b) {
    bf16x8 r;
    r[0] = (short)f2b(a.x); r[1] = (short)f2b(a.y);
    r[2] = (short)f2b(a.z); r[3] = (short)f2b(a.w);
    r[4] = (short)f2b(b.x); r[5] = (short)f2b(b.y);
    r[6] = (short)f2b(b.z); r[7] = (short)f2b(b.w);
    return r;
}

// LDS weight addressing: [4][64][64] bf16, row = 128 B.
// XOR swizzle: elem col ^= (row&7)<<3 (byte ^= (row&7)<<4).
__device__ __forceinline__ int swz(int row, int col) {
    return row * 64 + (col ^ ((row & 7) << 3));
}

// ---- pre-kernel: convert weights fp32 -> bf16 into d_ws; Wq scaled by 1/8 ----
__global__ void cvt_w_kernel(const float* __restrict__ wk, const float* __restrict__ wq,
                             const float* __restrict__ wv, const float* __restrict__ wp,
                             unsigned short* __restrict__ dst) {
    int e = blockIdx.x * 256 + threadIdx.x;   // 0..16383
    int m = e >> 12;
    int off = e & 4095;
    const float* src = (m == 0) ? wk : (m == 1) ? wq : (m == 2) ? wv : wp;
    float s = (m == 1) ? 0.125f : 1.0f;       // 2^-3: exact in bf16
    dst[e] = f2b(src[off] * s);
}

// One full batch. xf in regs; output bounced through bnc (wave-private LDS).
__device__ __forceinline__ void compute_batch(
    const short* __restrict__ lw, float* __restrict__ bnc, const bf16x8 xf[8],
    const float* __restrict__ bp, float* __restrict__ ob, int lane, int r, int g)
{
    const short* Wk = lw;
    const short* Wq = lw + 4096;
    const short* Wv = lw + 8192;
    const short* Wp = lw + 12288;

    // kT = Wk @ xT
    bf16x8 kT8[2][4];
    #pragma unroll
    for (int cm2 = 0; cm2 < 2; ++cm2) {
        bf16x4 lo[4];
        #pragma unroll
        for (int h = 0; h < 2; ++h) {
            const int cm = cm2 * 2 + h;
            bf16x8 a0 = *(const bf16x8*)(Wk + swz(cm * 16 + r, g * 8));
            bf16x8 a1 = *(const bf16x8*)(Wk + swz(cm * 16 + r, 32 + g * 8));
            #pragma unroll
            for (int sm = 0; sm < 4; ++sm) {
                f32x4 acc = {0.f, 0.f, 0.f, 0.f};
                acc = MFMA32(a0, xf[sm * 2], acc);
                acc = MFMA32(a1, xf[sm * 2 + 1], acc);
                if (h == 0) lo[sm] = pack4(acc, 1.0f);
                else kT8[cm2][sm] = cat(lo[sm], pack4(acc, 1.0f));
            }
        }
    }

    // qT = (Wq/8) @ xT
    bf16x8 q8[2][4];
    #pragma unroll
    for (int cm2 = 0; cm2 < 2; ++cm2) {
        bf16x4 lo[4];
        #pragma unroll
        for (int h = 0; h < 2; ++h) {
            const int cm = cm2 * 2 + h;
            bf16x8 a0 = *(const bf16x8*)(Wq + swz(cm * 16 + r, g * 8));
            bf16x8 a1 = *(const bf16x8*)(Wq + swz(cm * 16 + r, 32 + g * 8));
            #pragma unroll
            for (int tt = 0; tt < 4; ++tt) {
                f32x4 acc = {0.f, 0.f, 0.f, 0.f};
                acc = MFMA32(a0, xf[tt * 2], acc);
                acc = MFMA32(a1, xf[tt * 2 + 1], acc);
                if (h == 0) lo[tt] = pack4(acc, 1.0f);
                else q8[cm2][tt] = cat(lo[tt], pack4(acc, 1.0f));
            }
        }
    }

    // scores + softmax -> P  (lane: col t = tn*16+r, rows s = sm*16+g*4+j)
    bf16x4 P[4][4];
    #pragma unroll
    for (int tn = 0; tn < 4; ++tn) {
        f32x4 st[4];
        #pragma unroll
        for (int sm = 0; sm < 4; ++sm) {
            if (sm > tn) continue;
            f32x4 acc = {0.f, 0.f, 0.f, 0.f};
            acc = MFMA32(kT8[0][sm], q8[0][tn], acc);
            acc = MFMA32(kT8[1][sm], q8[1][tn], acc);
            st[sm] = acc;
        }
        float mx = -1e30f;
        #pragma unroll
        for (int sm = 0; sm < 4; ++sm) {
            if (sm > tn) continue;
            #pragma unroll
            for (int j = 0; j < 4; ++j) {
                float v = st[sm][j];
                if (sm == tn) v = ((g * 4 + j) <= r) ? v : -1e30f;  // causal
                st[sm][j] = v;
                mx = fmaxf(mx, v);
            }
        }
        mx = fmaxf(mx, __shfl_xor(mx, 16));
        mx = fmaxf(mx, __shfl_xor(mx, 32));
        float sum = 0.f;
        #pragma unroll
        for (int sm = 0; sm < 4; ++sm) {
            if (sm > tn) continue;
            #pragma unroll
            for (int j = 0; j < 4; ++j) {
                float e = exp2f((st[sm][j] - mx) * LOG2E);
                st[sm][j] = e;
                sum += e;
            }
        }
        sum += __shfl_xor(sum, 16);
        sum += __shfl_xor(sum, 32);
        float inv = __builtin_amdgcn_rcpf(sum);   // sum >= 1 (diagonal present)
        #pragma unroll
        for (int sm = 0; sm < 4; ++sm)
            P[sm][tn] = (sm <= tn) ? pack4(st[sm], inv) : zero4();
    }

    // v = x @ WvT
    bf16x8 v8[4][2];
    #pragma unroll
    for (int cm = 0; cm < 4; ++cm) {
        bf16x8 b0 = *(const bf16x8*)(Wv + swz(cm * 16 + r, g * 8));
        bf16x8 b1 = *(const bf16x8*)(Wv + swz(cm * 16 + r, 32 + g * 8));
        bf16x4 tmp[4];
        #pragma unroll
        for (int tv = 0; tv < 4; ++tv) {
            f32x4 acc = {0.f, 0.f, 0.f, 0.f};
            acc = MFMA32(xf[tv * 2], b0, acc);
            acc = MFMA32(xf[tv * 2 + 1], b1, acc);
            tmp[tv] = pack4(acc, 1.0f);
        }
        v8[cm][0] = cat(tmp[0], tmp[1]);
        v8[cm][1] = cat(tmp[2], tmp[3]);
    }

    // out2T = v * PT
    bf16x8 o28[4][2];
    #pragma unroll
    for (int tn = 0; tn < 4; ++tn) {
        bf16x8 pt80 = cat(P[0][tn], P[1][tn]);
        bf16x8 pt81 = cat(P[2][tn], P[3][tn]);
        bf16x4 c[4];
        #pragma unroll
        for (int cm = 0; cm < 4; ++cm) {
            f32x4 acc = {0.f, 0.f, 0.f, 0.f};
            acc = MFMA32(v8[cm][0], pt80, acc);
            if (tn >= 2) acc = MFMA32(v8[cm][1], pt81, acc);
            c[cm] = pack4(acc, 1.0f);
        }
        o28[tn][0] = cat(c[0], c[1]);
        o28[tn][1] = cat(c[2], c[3]);
    }

    // resT = Wp @ out2T + bias; bounce through LDS; coalesced 1KB stores.
    bf16x8 wp0[4], wp1[4];
    float4 bias4[4];
    #pragma unroll
    for (int om = 0; om < 4; ++om) {
        wp0[om] = cat(*(const bf16x4*)(Wp + swz(om * 16 + r, g * 4)),
                      *(const bf16x4*)(Wp + swz(om * 16 + r, 16 + g * 4)));
        wp1[om] = cat(*(const bf16x4*)(Wp + swz(om * 16 + r, 32 + g * 4)),
                      *(const bf16x4*)(Wp + swz(om * 16 + r, 48 + g * 4)));
        bias4[om] = *(const float4*)(bp + om * 16 + g * 4);
    }
    #pragma unroll
    for (int tn = 0; tn < 4; ++tn) {
        // frag: row t = tn*16+r, cols om*16+g*4+j -> LDS[r][om*16+g*4]
        #pragma unroll
        for (int om = 0; om < 4; ++om) {
            f32x4 acc = {0.f, 0.f, 0.f, 0.f};
            acc = MFMA32(wp0[om], o28[tn][0], acc);
            acc = MFMA32(wp1[om], o28[tn][1], acc);
            float4 o;
            o.x = acc[0] + bias4[om].x; o.y = acc[1] + bias4[om].y;
            o.z = acc[2] + bias4[om].z; o.w = acc[3] + bias4[om].w;
            *(float4*)(bnc + r * BSTR + om * 16 + g * 4) = o;
        }
        asm volatile("s_waitcnt lgkmcnt(0)" ::: "memory");  // writes visible wave-wide
        // read back linearly, store 4 x 1KB contiguous (full 128B lines)
        #pragma unroll
        for (int i = 0; i < 4; ++i) {
            float4 v = *(const float4*)(bnc + (i * 4 + (lane >> 4)) * BSTR + (lane & 15) * 4);
            *(float4*)(ob + tn * 1024 + i * 256 + lane * 4) = v;
        }
        asm volatile("" ::: "memory");  // keep next tn's LDS writes after these reads
    }
}

__global__ __launch_bounds__(256, 2) void attn_fused_kernel(
    const float* __restrict__ x,              // [4096,64,64] fp32
    const unsigned short* __restrict__ wbf,   // bf16: Wk, Wq(/8), Wv, Wp
    const float* __restrict__ bp,             // [64] fp32
    float* __restrict__ out)                  // [4096,64,64] fp32
{
    __shared__ short lw[16384];               // 32 KB weights, swizzled
    __shared__ float lbounce[4 * 16 * BSTR];  // 4 waves x 16-row bounce (17 KB)

    const int tid  = threadIdx.x;
    const int wv_  = tid >> 6;
    const int lane = tid & 63;
    const int r = lane & 15;
    const int g = lane >> 4;
    float* bnc = lbounce + wv_ * (16 * BSTR);
    const long b0 = (long)blockIdx.x * 4 + wv_;     // [0, 2048)
    const long b1 = b0 + 2048;

    // ---- issue batch-0 x loads ----
    const float* xb0 = x + b0 * 4096;
    float4 raw[8][2];
    #pragma unroll
    for (int f = 0; f < 8; ++f) {
        const float* p = xb0 + ((f >> 1) * 16 + r) * 64 + (f & 1) * 32 + g * 8;
        raw[f][0] = *(const float4*)p;
        raw[f][1] = *(const float4*)(p + 4);
    }

    // ---- stage weights to LDS (swizzled), 128 B per thread ----
    {
        const int rw = tid;
        #pragma unroll
        for (int i = 0; i < 8; ++i) {
            bf16x8 v = *(const bf16x8*)(wbf + rw * 64 + i * 8);
            *(bf16x8*)(lw + rw * 64 + ((i ^ (rw & 7)) * 8)) = v;
        }
    }

    // ---- convert batch-0 x to bf16 frags ----
    bf16x8 xf[8];
    #pragma unroll
    for (int f = 0; f < 8; ++f)
        xf[f] = cvt8(raw[f][0], raw[f][1]);

    __syncthreads();                          // weights visible (drains vmem too)

    // ---- PREFETCH batch-1 x: flies under batch-0's whole compute ----
    const float* xb1 = x + b1 * 4096;
    float4 raw1[8][2];
    #pragma unroll
    for (int f = 0; f < 8; ++f) {
        const float* p = xb1 + ((f >> 1) * 16 + r) * 64 + (f & 1) * 32 + g * 8;
        raw1[f][0] = *(const float4*)p;
        raw1[f][1] = *(const float4*)(p + 4);
    }

    // ---- batch 0: compute + store (stores drain under batch 1) ----
    compute_batch(lw, bnc, xf, bp, out + b0 * 4096, lane, r, g);

    // ---- batch 1: convert (waits prefetch), compute + store ----
    bf16x8 xf1[8];
    #pragma unroll
    for (int f = 0; f < 8; ++f)
        xf1[f] = cvt8(raw1[f][0], raw1[f][1]);

    compute_batch(lw, bnc, xf1, bp, out + b1 * 4096, lane, r, g);
}

extern "C" void kernel_launch(void* const* d_in, const int* in_sizes, int n_in,
                              void* d_out, int out_size, void* d_ws, size_t ws_size,
                              hipStream_t stream) {
    const float* x  = (const float*)d_in[0];
    const float* wk = (const float*)d_in[1];
    const float* wq = (const float*)d_in[2];
    const float* wv = (const float*)d_in[3];
    const float* wp = (const float*)d_in[4];
    const float* bp = (const float*)d_in[5];
    unsigned short* wbf = (unsigned short*)d_ws;   // 16384 bf16 = 32 KB

    cvt_w_kernel<<<64, 256, 0, stream>>>(wk, wq, wv, wp, wbf);
    attn_fused_kernel<<<512, 256, 0, stream>>>(x, wbf, bp, (float*)d_out);
}